// Round 1
// baseline (365.819 us; speedup 1.0000x reference)
//
#include <hip/hip_runtime.h>
#include <cstdint>
#include <cstddef>

#define D_MODEL 2048
#define SEQ 2048
#define BATCH 2
#define HEADS 16
#define DH 128
#define MROWS (BATCH * SEQ) /* 4096 */

typedef __attribute__((ext_vector_type(8))) short short8;
typedef __attribute__((ext_vector_type(4))) float f32x4;

__device__ __forceinline__ unsigned short f2bf(float f) {
    unsigned int u = __builtin_bit_cast(unsigned int, f);
    u += 0x7fffu + ((u >> 16) & 1u);   // round-to-nearest-even
    return (unsigned short)(u >> 16);
}

__device__ __forceinline__ void gload_lds16(const unsigned short* g, unsigned short* l) {
    __builtin_amdgcn_global_load_lds(
        (const __attribute__((address_space(1))) void*)g,
        (__attribute__((address_space(3))) void*)l, 16, 0, 0);
}

// ---------------- fp32 -> bf16 conversion ----------------
__global__ __launch_bounds__(256) void cvt_kernel(const float* __restrict__ in,
                                                  unsigned short* __restrict__ out, int n4) {
    int i = blockIdx.x * 256 + threadIdx.x;
    if (i < n4) {
        const float4 v = reinterpret_cast<const float4*>(in)[i];
        ushort4 o;
        o.x = f2bf(v.x); o.y = f2bf(v.y); o.z = f2bf(v.z); o.w = f2bf(v.w);
        reinterpret_cast<ushort4*>(out)[i] = o;
    }
}

// ---------------- GEMM: C[m][n] = sum_k A[m][k]*B[n][k] + bias[n] ----------------
// A: [M][K] bf16 row-major, B: [N][K] bf16 row-major (weights, B^T layout).
// m97 structure: 128x128 tile, BK=64, 4 waves (2x2), global_load_lds w=16,
// chunk-XOR swizzle (chunk ^= row&7) on both stage-source and read.
template <typename OUT_T>
__global__ __launch_bounds__(256, 2)
void gemm_bt(const unsigned short* __restrict__ A, const unsigned short* __restrict__ B,
             const float* __restrict__ bias, OUT_T* __restrict__ C,
             int M, int N, int K) {
    constexpr int BM = 128, BN = 128, BK = 64;
    __shared__ unsigned short As[BM * BK];
    __shared__ unsigned short Bs[BN * BK];

    const int tid  = threadIdx.x;
    const int lane = tid & 63;
    const int wid  = tid >> 6;
    const int ntile = N / BN;
    const int mt = blockIdx.x / ntile;
    const int nt = blockIdx.x % ntile;
    const int m0 = mt * BM, n0 = nt * BN;

    f32x4 acc[4][4] = {};

    const int srow = wid * 32 + (lane >> 3);  // staging row (+ j*8)
    const int schk = lane & 7;                // staging 16B-chunk
    const int wr = wid >> 1, wc = wid & 1;    // wave 2x2 grid
    const int fr = lane & 15;                 // fragment row/col
    const int fg = lane >> 4;                 // fragment k-group

    for (int k0 = 0; k0 < K; k0 += BK) {
#pragma unroll
        for (int j = 0; j < 4; ++j) {
            const int row = srow + j * 8;
            const int gch = schk ^ (row & 7);  // inverse-swizzled source
            gload_lds16(A + (size_t)(m0 + row) * K + k0 + gch * 8,
                        As + (wid * 32 + j * 8) * BK);
            gload_lds16(B + (size_t)(n0 + row) * K + k0 + gch * 8,
                        Bs + (wid * 32 + j * 8) * BK);
        }
        __syncthreads();
#pragma unroll
        for (int kk = 0; kk < 2; ++kk) {
            short8 af[4], bf[4];
#pragma unroll
            for (int i = 0; i < 4; ++i) {
                const int ra = wr * 64 + i * 16 + fr;
                af[i] = *(const short8*)&As[ra * BK + (((kk * 4) + fg) ^ (ra & 7)) * 8];
                const int rb = wc * 64 + i * 16 + fr;
                bf[i] = *(const short8*)&Bs[rb * BK + (((kk * 4) + fg) ^ (rb & 7)) * 8];
            }
#pragma unroll
            for (int mi = 0; mi < 4; ++mi)
#pragma unroll
                for (int ni = 0; ni < 4; ++ni)
                    acc[mi][ni] = __builtin_amdgcn_mfma_f32_16x16x32_bf16(
                        af[mi], bf[ni], acc[mi][ni], 0, 0, 0);
        }
        __syncthreads();
    }

#pragma unroll
    for (int mi = 0; mi < 4; ++mi) {
#pragma unroll
        for (int ni = 0; ni < 4; ++ni) {
            const int col = n0 + wc * 64 + ni * 16 + fr;
            const float bv = bias[col];
#pragma unroll
            for (int r = 0; r < 4; ++r) {
                const int row = m0 + wr * 64 + mi * 16 + fg * 4 + r;
                const float v = acc[mi][ni][r] + bv;
                if constexpr (sizeof(OUT_T) == 2) {
                    C[(size_t)row * N + col] = (OUT_T)f2bf(v);
                } else {
                    C[(size_t)row * N + col] = v;
                }
            }
        }
    }
}

// ---------------- flash attention ----------------
// Per block: one (b,h), one 128-row Q tile. 4 waves x 32 q-rows.
// K tile [64][128] swizzled LDS; V transposed to Vt[128][72-pad];
// P through Pl[128][72-pad] to convert C-layout -> A-layout.
__global__ __launch_bounds__(256, 2)
void flash_attn(const unsigned short* __restrict__ Q, const unsigned short* __restrict__ Kg,
                const unsigned short* __restrict__ Vg, unsigned short* __restrict__ O) {
    constexpr int KB = 64;
    __shared__ unsigned short Ks[KB * DH];     // 16 KB, chunk-swizzled
    __shared__ unsigned short Vt[DH * 72];     // 18 KB, V^T padded
    __shared__ unsigned short Pl[128 * 72];    // 18 KB, P padded

    const int tid  = threadIdx.x;
    const int lane = tid & 63;
    const int wid  = tid >> 6;
    const int fr = lane & 15, fg = lane >> 4;

    const int qt = blockIdx.x & 15;
    const int bh = blockIdx.x >> 4;
    const int b = bh >> 4, h = bh & 15;
    const int q0 = qt * 128;
    const int qr = wid * 32;

    const unsigned short* Qp = Q + (size_t)b * SEQ * D_MODEL + h * DH;
    const unsigned short* Kp = Kg + (size_t)b * SEQ * D_MODEL + h * DH;
    const unsigned short* Vp = Vg + (size_t)b * SEQ * D_MODEL + h * DH;

    // Q fragments in registers (A-operand layout)
    short8 qf[2][4];
#pragma unroll
    for (int mf = 0; mf < 2; ++mf)
#pragma unroll
        for (int kk = 0; kk < 4; ++kk) {
            const int s = q0 + qr + mf * 16 + fr;
            qf[mf][kk] = *(const short8*)(Qp + (size_t)s * D_MODEL + kk * 32 + fg * 8);
        }

    f32x4 acc_o[2][8] = {};
    float m_run[2][4], l_run[2][4];
#pragma unroll
    for (int mf = 0; mf < 2; ++mf)
#pragma unroll
        for (int r = 0; r < 4; ++r) { m_run[mf][r] = -1e30f; l_run[mf][r] = 0.f; }

    const float scale = 0.08838834764831845f;  // 1/sqrt(128)

    for (int t = 0; t < SEQ / KB; ++t) {
        const int kv0 = t * KB;
        // ---- stage K tile (swizzled source -> linear LDS) ----
#pragma unroll
        for (int j = 0; j < 4; ++j) {
            const int row = wid * 16 + j * 4 + (lane >> 4);
            const int gch = (lane & 15) ^ (row & 7);
            gload_lds16(Kp + (size_t)(kv0 + row) * D_MODEL + gch * 8,
                        Ks + (wid * 16 + j * 4) * DH);
        }
        // ---- V tile: load 2 rows x 8 cols, pack pairs, write transposed ----
#pragma unroll
        for (int j = 0; j < 2; ++j) {
            const int u = j * 256 + tid;
            const int r = (u & 31) * 2, c = (u >> 5) * 8;
            const unsigned short* src = Vp + (size_t)(kv0 + r) * D_MODEL + c;
            const short8 v0 = *(const short8*)src;
            const short8 v1 = *(const short8*)(src + D_MODEL);
#pragma unroll
            for (int i = 0; i < 8; ++i) {
                const unsigned int w = (unsigned int)(unsigned short)v0[i] |
                                       ((unsigned int)(unsigned short)v1[i] << 16);
                *(unsigned int*)&Vt[(c + i) * 72 + r] = w;
            }
        }
        __syncthreads();

        // ---- QK^T ----
        f32x4 sc[2][4] = {};
#pragma unroll
        for (int kk = 0; kk < 4; ++kk) {
            short8 bfr[4];
#pragma unroll
            for (int nf = 0; nf < 4; ++nf) {
                const int row = nf * 16 + fr;
                bfr[nf] = *(const short8*)&Ks[row * DH + (((kk * 4) + fg) ^ (row & 7)) * 8];
            }
#pragma unroll
            for (int mf = 0; mf < 2; ++mf)
#pragma unroll
                for (int nf = 0; nf < 4; ++nf)
                    sc[mf][nf] = __builtin_amdgcn_mfma_f32_16x16x32_bf16(
                        qf[mf][kk], bfr[nf], sc[mf][nf], 0, 0, 0);
        }
#pragma unroll
        for (int mf = 0; mf < 2; ++mf)
#pragma unroll
            for (int nf = 0; nf < 4; ++nf) sc[mf][nf] *= scale;

        // ---- online softmax + P write (rows in 16-lane segments) ----
#pragma unroll
        for (int mf = 0; mf < 2; ++mf) {
#pragma unroll
            for (int r = 0; r < 4; ++r) {
                float tm = fmaxf(fmaxf(sc[mf][0][r], sc[mf][1][r]),
                                 fmaxf(sc[mf][2][r], sc[mf][3][r]));
#pragma unroll
                for (int off = 1; off < 16; off <<= 1) tm = fmaxf(tm, __shfl_xor(tm, off, 16));
                const float mo = m_run[mf][r];
                const float mn = fmaxf(mo, tm);
                const float sf = __expf(mo - mn);
                m_run[mf][r] = mn;
                float ps = 0.f;
                const int prow = qr + mf * 16 + fg * 4 + r;
#pragma unroll
                for (int nf = 0; nf < 4; ++nf) {
                    const float p = __expf(sc[mf][nf][r] - mn);
                    ps += p;
                    Pl[prow * 72 + nf * 16 + fr] = f2bf(p);
                }
#pragma unroll
                for (int off = 1; off < 16; off <<= 1) ps += __shfl_xor(ps, off, 16);
                l_run[mf][r] = l_run[mf][r] * sf + ps;
#pragma unroll
                for (int df = 0; df < 8; ++df) acc_o[mf][df][r] *= sf;
            }
        }

        // ---- PV (same-wave Pl write->read, compiler orders via lgkmcnt) ----
#pragma unroll
        for (int kk = 0; kk < 2; ++kk) {
            short8 pf[2];
#pragma unroll
            for (int mf = 0; mf < 2; ++mf)
                pf[mf] = *(const short8*)&Pl[(qr + mf * 16 + fr) * 72 + kk * 32 + fg * 8];
#pragma unroll
            for (int df = 0; df < 8; ++df) {
                const short8 vf = *(const short8*)&Vt[(df * 16 + fr) * 72 + kk * 32 + fg * 8];
#pragma unroll
                for (int mf = 0; mf < 2; ++mf)
                    acc_o[mf][df] = __builtin_amdgcn_mfma_f32_16x16x32_bf16(
                        pf[mf], vf, acc_o[mf][df], 0, 0, 0);
            }
        }
        __syncthreads();
    }

    // ---- epilogue: O /= l, write bf16 [4096][2048] at (b*SEQ+s, h*DH+d) ----
#pragma unroll
    for (int mf = 0; mf < 2; ++mf)
#pragma unroll
        for (int df = 0; df < 8; ++df)
#pragma unroll
            for (int r = 0; r < 4; ++r) {
                const int s = q0 + qr + mf * 16 + fg * 4 + r;
                const float v = acc_o[mf][df][r] / l_run[mf][r];
                O[((size_t)b * SEQ + s) * D_MODEL + h * DH + df * 16 + fr] = f2bf(v);
            }
}

// ---------------- host launch ----------------
extern "C" void kernel_launch(void* const* d_in, const int* in_sizes, int n_in,
                              void* d_out, int out_size, void* d_ws, size_t ws_size,
                              hipStream_t stream) {
    (void)in_sizes; (void)n_in; (void)out_size; (void)ws_size;
    const float* x  = (const float*)d_in[0];
    const float* wq = (const float*)d_in[1];
    const float* bq = (const float*)d_in[2];
    const float* wk = (const float*)d_in[3];
    const float* bk = (const float*)d_in[4];
    const float* wv = (const float*)d_in[5];
    const float* bv = (const float*)d_in[6];
    const float* wo = (const float*)d_in[7];
    const float* bo = (const float*)d_in[8];
    float* out = (float*)d_out;

    unsigned short* ws = (unsigned short*)d_ws;
    const size_t NX = (size_t)MROWS * D_MODEL;    // 8,388,608
    const size_t NW = (size_t)D_MODEL * D_MODEL;  // 4,194,304
    unsigned short* xb  = ws;
    unsigned short* wqb = xb + NX;
    unsigned short* wkb = wqb + NW;
    unsigned short* wvb = wkb + NW;
    unsigned short* wob = wvb + NW;
    unsigned short* Qb  = wob + NW;
    unsigned short* Kb  = Qb + NX;
    unsigned short* Vb  = Kb + NX;
    unsigned short* Ab  = Vb + NX;   // total 117.4 MB of ws

    cvt_kernel<<<(unsigned)(NX / 1024), 256, 0, stream>>>(x,  xb,  (int)(NX / 4));
    cvt_kernel<<<(unsigned)(NW / 1024), 256, 0, stream>>>(wq, wqb, (int)(NW / 4));
    cvt_kernel<<<(unsigned)(NW / 1024), 256, 0, stream>>>(wk, wkb, (int)(NW / 4));
    cvt_kernel<<<(unsigned)(NW / 1024), 256, 0, stream>>>(wv, wvb, (int)(NW / 4));
    cvt_kernel<<<(unsigned)(NW / 1024), 256, 0, stream>>>(wo, wob, (int)(NW / 4));

    gemm_bt<unsigned short><<<512, 256, 0, stream>>>(xb, wqb, bq, Qb, MROWS, D_MODEL, D_MODEL);
    gemm_bt<unsigned short><<<512, 256, 0, stream>>>(xb, wkb, bk, Kb, MROWS, D_MODEL, D_MODEL);
    gemm_bt<unsigned short><<<512, 256, 0, stream>>>(xb, wvb, bv, Vb, MROWS, D_MODEL, D_MODEL);

    flash_attn<<<512, 256, 0, stream>>>(Qb, Kb, Vb, Ab);

    gemm_bt<float><<<512, 256, 0, stream>>>(Ab, wob, bo, out, MROWS, D_MODEL, D_MODEL);
}

// Round 2
// 302.986 us; speedup vs baseline: 1.2074x; 1.2074x over previous
//
#include <hip/hip_runtime.h>
#include <cstdint>
#include <cstddef>

#define D_MODEL 2048
#define SEQ 2048
#define BATCH 2
#define HEADS 16
#define DH 128
#define MROWS (BATCH * SEQ) /* 4096 */

typedef __attribute__((ext_vector_type(8))) short short8;
typedef __attribute__((ext_vector_type(4))) float f32x4;
typedef __attribute__((ext_vector_type(16))) float f32x16;

__device__ __forceinline__ unsigned short f2bf(float f) {
    unsigned int u = __builtin_bit_cast(unsigned int, f);
    u += 0x7fffu + ((u >> 16) & 1u);   // round-to-nearest-even
    return (unsigned short)(u >> 16);
}

__device__ __forceinline__ unsigned int pk2(float lo, float hi2) {
    return (unsigned int)f2bf(lo) | ((unsigned int)f2bf(hi2) << 16);
}

__device__ __forceinline__ void gload_lds16(const unsigned short* g, unsigned short* l) {
    __builtin_amdgcn_global_load_lds(
        (const __attribute__((address_space(1))) void*)g,
        (__attribute__((address_space(3))) void*)l, 16, 0, 0);
}

// ---------------- fp32 -> bf16 conversion ----------------
__global__ __launch_bounds__(256) void cvt_kernel(const float* __restrict__ in,
                                                  unsigned short* __restrict__ out, int n4) {
    int i = blockIdx.x * 256 + threadIdx.x;
    if (i < n4) {
        const float4 v = reinterpret_cast<const float4*>(in)[i];
        ushort4 o;
        o.x = f2bf(v.x); o.y = f2bf(v.y); o.z = f2bf(v.z); o.w = f2bf(v.w);
        reinterpret_cast<ushort4*>(out)[i] = o;
    }
}

// ---------------- GEMM: C[m][n] = sum_k A[m][k]*B[n][k] + bias[n] ----------------
// MODE 0: float out row-major. MODE 1: bf16 out row-major. MODE 2: bf16 out TRANSPOSED
// (C^T stored [N][M], packed 4-row stores) — used for V so flash can stage V^T directly.
template <int MODE, typename OUT_T>
__global__ __launch_bounds__(256, 2)
void gemm_bt(const unsigned short* __restrict__ A, const unsigned short* __restrict__ B,
             const float* __restrict__ bias, OUT_T* __restrict__ C,
             int M, int N, int K) {
    constexpr int BM = 128, BN = 128, BK = 64;
    __shared__ unsigned short As[BM * BK];
    __shared__ unsigned short Bs[BN * BK];

    const int tid  = threadIdx.x;
    const int lane = tid & 63;
    const int wid  = tid >> 6;
    const int ntile = N / BN;
    const int mt = blockIdx.x / ntile;
    const int nt = blockIdx.x % ntile;
    const int m0 = mt * BM, n0 = nt * BN;

    f32x4 acc[4][4] = {};

    const int srow = wid * 32 + (lane >> 3);  // staging row (+ j*8)
    const int schk = lane & 7;                // staging 16B-chunk
    const int wr = wid >> 1, wc = wid & 1;    // wave 2x2 grid
    const int fr = lane & 15;                 // fragment row/col
    const int fg = lane >> 4;                 // fragment k-group

    for (int k0 = 0; k0 < K; k0 += BK) {
#pragma unroll
        for (int j = 0; j < 4; ++j) {
            const int row = srow + j * 8;
            const int gch = schk ^ (row & 7);  // inverse-swizzled source
            gload_lds16(A + (size_t)(m0 + row) * K + k0 + gch * 8,
                        As + (wid * 32 + j * 8) * BK);
            gload_lds16(B + (size_t)(n0 + row) * K + k0 + gch * 8,
                        Bs + (wid * 32 + j * 8) * BK);
        }
        __syncthreads();
#pragma unroll
        for (int kk = 0; kk < 2; ++kk) {
            short8 af[4], bf[4];
#pragma unroll
            for (int i = 0; i < 4; ++i) {
                const int ra = wr * 64 + i * 16 + fr;
                af[i] = *(const short8*)&As[ra * BK + (((kk * 4) + fg) ^ (ra & 7)) * 8];
                const int rb = wc * 64 + i * 16 + fr;
                bf[i] = *(const short8*)&Bs[rb * BK + (((kk * 4) + fg) ^ (rb & 7)) * 8];
            }
#pragma unroll
            for (int mi = 0; mi < 4; ++mi)
#pragma unroll
                for (int ni = 0; ni < 4; ++ni)
                    acc[mi][ni] = __builtin_amdgcn_mfma_f32_16x16x32_bf16(
                        af[mi], bf[ni], acc[mi][ni], 0, 0, 0);
        }
        __syncthreads();
    }

#pragma unroll
    for (int mi = 0; mi < 4; ++mi) {
#pragma unroll
        for (int ni = 0; ni < 4; ++ni) {
            const int col = n0 + wc * 64 + ni * 16 + fr;
            const float bv = bias[col];
            if constexpr (MODE == 2) {
                const int row_b = m0 + wr * 64 + mi * 16 + fg * 4;
                ushort4 o4;
                o4.x = f2bf(acc[mi][ni][0] + bv);
                o4.y = f2bf(acc[mi][ni][1] + bv);
                o4.z = f2bf(acc[mi][ni][2] + bv);
                o4.w = f2bf(acc[mi][ni][3] + bv);
                *(ushort4*)&C[(size_t)col * M + row_b] = o4;
            } else {
#pragma unroll
                for (int r = 0; r < 4; ++r) {
                    const int row = m0 + wr * 64 + mi * 16 + fg * 4 + r;
                    const float v = acc[mi][ni][r] + bv;
                    if constexpr (MODE == 1) {
                        C[(size_t)row * N + col] = (OUT_T)f2bf(v);
                    } else {
                        C[(size_t)row * N + col] = v;
                    }
                }
            }
        }
    }
}

// ---------------- flash attention v2: swapped-operand 32x32x16 ----------------
// 4 waves x 32 q-rows = 128 q/block; KVB=64. Swapped QK^T (lane owns one q-row),
// in-register softmax (1 shfl per reduction), P->B-frag via pack + half-swap shfl,
// swapped PV (O^T accumulate, per-lane scalar rescale). V^T staged from global VT.
__global__ __launch_bounds__(256, 2)
void flash_attn2(const unsigned short* __restrict__ Q, const unsigned short* __restrict__ Kg,
                 const unsigned short* __restrict__ VT, unsigned short* __restrict__ O) {
    constexpr int KVB = 64;
    __shared__ unsigned short Ks[KVB * DH];   // [64 kv][128 d], chunk^(row&7) swizzled
    __shared__ unsigned short Vs[DH * KVB];   // [128 d][64 kv] (V^T), chunk^(d&7) swizzled

    const int tid  = threadIdx.x;
    const int lane = tid & 63;
    const int wid  = tid >> 6;
    const int l31  = lane & 31;
    const int hi   = lane >> 5;

    const int qt = blockIdx.x & 15;
    const int bh = blockIdx.x >> 4;
    const int b = bh >> 4, h = bh & 15;
    const int qrow = qt * 128 + wid * 32 + l31;   // this lane's q-row

    const unsigned short* Qp = Q + ((size_t)b * SEQ + qrow) * D_MODEL + h * DH;
    const unsigned short* Kp = Kg + (size_t)b * SEQ * D_MODEL + h * DH;
    const unsigned short* Vp = VT + (size_t)(h * DH) * MROWS + (size_t)b * SEQ;

    // Q B-frags: lane holds Q[q=own][d = kk*16 + hi*8 .. +7]
    short8 qf[8];
#pragma unroll
    for (int kk = 0; kk < 8; ++kk)
        qf[kk] = *(const short8*)(Qp + kk * 16 + hi * 8);

    f32x16 acc[4] = {};           // O^T: acc[db] reg r -> O[q=own][d = db*32 + crow(r,hi)]
    float m_run = -1e30f, l_run = 0.f;
    const float Cc = 0.088388347648318447f * 1.4426950408889634f;  // scale * log2(e)

    // staging source offsets (inverse-swizzled; LDS dest is linear)
    int kroff[4];
#pragma unroll
    for (int q = 0; q < 4; ++q) {
        const int row_l = wid * 16 + q * 4 + (lane >> 4);
        kroff[q] = row_l * D_MODEL + ((lane & 15) ^ (row_l & 7)) * 8;
    }
    int vroff[4];
#pragma unroll
    for (int q = 0; q < 4; ++q) {
        const int d_l = wid * 32 + q * 8 + (lane >> 3);
        vroff[q] = d_l * MROWS + ((lane & 7) ^ (d_l & 7)) * 8;
    }
    unsigned short* KsW = Ks + (wid * 16) * DH;
    unsigned short* VsW = Vs + (wid * 32) * KVB;

    for (int t = 0; t < SEQ / KVB; ++t) {
        const unsigned short* Kt = Kp + (size_t)(t * KVB) * D_MODEL;
        const unsigned short* Vt = Vp + t * KVB;
#pragma unroll
        for (int q = 0; q < 4; ++q) {
            gload_lds16(Kt + kroff[q], KsW + q * 4 * DH);
            gload_lds16(Vt + vroff[q], VsW + q * 8 * KVB);
        }
        __syncthreads();

        // ---- swapped QK^T: St[kv][q], col=lane&31=q ----
        f32x16 st0 = {}, st1 = {};
#pragma unroll
        for (int kk = 0; kk < 8; ++kk) {
            const int sw = (((kk * 2 + hi) ^ (lane & 7))) * 8;
            const short8 kf0 = *(const short8*)&Ks[(l31) * DH + sw];
            const short8 kf1 = *(const short8*)&Ks[(32 + l31) * DH + sw];
            st0 = __builtin_amdgcn_mfma_f32_32x32x16_bf16(kf0, qf[kk], st0, 0, 0, 0);
            st1 = __builtin_amdgcn_mfma_f32_32x32x16_bf16(kf1, qf[kk], st1, 0, 0, 0);
        }

        // ---- in-register online softmax (raw scores; scale folded into exp2) ----
        float lm = -1e30f;
#pragma unroll
        for (int r = 0; r < 16; ++r) { lm = fmaxf(lm, st0[r]); lm = fmaxf(lm, st1[r]); }
        lm = fmaxf(lm, __shfl_xor(lm, 32));
        const float mn = fmaxf(m_run, lm);
        const float sf = exp2f((m_run - mn) * Cc);
        m_run = mn;
        const float mc = mn * Cc;
        float ps = 0.f;
        float p0[16], p1[16];
#pragma unroll
        for (int r = 0; r < 16; ++r) {
            p0[r] = exp2f(__builtin_fmaf(st0[r], Cc, -mc));
            p1[r] = exp2f(__builtin_fmaf(st1[r], Cc, -mc));
            ps += p0[r] + p1[r];
        }
        ps += __shfl_xor(ps, 32);
        l_run = l_run * sf + ps;
#pragma unroll
        for (int db = 0; db < 4; ++db)
#pragma unroll
            for (int r = 0; r < 16; ++r) acc[db][r] *= sf;

        // ---- P -> bf16 packed words; build PV B-frags via half-swap exchange ----
        unsigned int W0[8], W1[8];
#pragma unroll
        for (int tt = 0; tt < 8; ++tt) {
            W0[tt] = pk2(p0[2 * tt], p0[2 * tt + 1]);
            W1[tt] = pk2(p1[2 * tt], p1[2 * tt + 1]);
        }
        short8 pf[4];
#pragma unroll
        for (int kk16 = 0; kk16 < 4; ++kk16) {
            const unsigned int* W = (kk16 < 2) ? W0 : W1;
            const int c = kk16 & 1;
            const unsigned int self0 = hi ? W[4 * c + 2] : W[4 * c + 0];
            const unsigned int self1 = hi ? W[4 * c + 3] : W[4 * c + 1];
            const unsigned int send0 = hi ? W[4 * c + 0] : W[4 * c + 2];
            const unsigned int send1 = hi ? W[4 * c + 1] : W[4 * c + 3];
            const unsigned int got0 = (unsigned int)__shfl_xor((int)send0, 32);
            const unsigned int got1 = (unsigned int)__shfl_xor((int)send1, 32);
            uint4 fw;
            fw.x = hi ? got0 : self0;
            fw.y = hi ? got1 : self1;
            fw.z = hi ? self0 : got0;
            fw.w = hi ? self1 : got1;
            pf[kk16] = __builtin_bit_cast(short8, fw);
        }

        // ---- swapped PV: O^T[d][q] += V^T-frag x P-frag ----
        __builtin_amdgcn_s_setprio(1);
#pragma unroll
        for (int db = 0; db < 4; ++db) {
#pragma unroll
            for (int kk16 = 0; kk16 < 4; ++kk16) {
                const int sw = (((kk16 * 2 + hi) ^ (lane & 7))) * 8;
                const short8 vf = *(const short8*)&Vs[(db * 32 + l31) * KVB + sw];
                acc[db] = __builtin_amdgcn_mfma_f32_32x32x16_bf16(vf, pf[kk16], acc[db], 0, 0, 0);
            }
        }
        __builtin_amdgcn_s_setprio(0);
        __syncthreads();
    }

    // ---- epilogue: per-lane scalar 1/l; packed 4-wide bf16 stores ----
    const float inv_l = 1.0f / l_run;
    unsigned short* Op = O + ((size_t)b * SEQ + qrow) * D_MODEL + h * DH;
#pragma unroll
    for (int db = 0; db < 4; ++db)
#pragma unroll
        for (int g = 0; g < 4; ++g) {
            ushort4 o4;
            o4.x = f2bf(acc[db][4 * g + 0] * inv_l);
            o4.y = f2bf(acc[db][4 * g + 1] * inv_l);
            o4.z = f2bf(acc[db][4 * g + 2] * inv_l);
            o4.w = f2bf(acc[db][4 * g + 3] * inv_l);
            *(ushort4*)(Op + db * 32 + g * 8 + hi * 4) = o4;
        }
}

// ---------------- host launch ----------------
extern "C" void kernel_launch(void* const* d_in, const int* in_sizes, int n_in,
                              void* d_out, int out_size, void* d_ws, size_t ws_size,
                              hipStream_t stream) {
    (void)in_sizes; (void)n_in; (void)out_size; (void)ws_size;
    const float* x  = (const float*)d_in[0];
    const float* wq = (const float*)d_in[1];
    const float* bq = (const float*)d_in[2];
    const float* wk = (const float*)d_in[3];
    const float* bk = (const float*)d_in[4];
    const float* wv = (const float*)d_in[5];
    const float* bv = (const float*)d_in[6];
    const float* wo = (const float*)d_in[7];
    const float* bo = (const float*)d_in[8];
    float* out = (float*)d_out;

    unsigned short* ws = (unsigned short*)d_ws;
    const size_t NX = (size_t)MROWS * D_MODEL;    // 8,388,608
    const size_t NW = (size_t)D_MODEL * D_MODEL;  // 4,194,304
    unsigned short* xb  = ws;
    unsigned short* wqb = xb + NX;
    unsigned short* wkb = wqb + NW;
    unsigned short* wvb = wkb + NW;
    unsigned short* wob = wvb + NW;
    unsigned short* Qb  = wob + NW;
    unsigned short* Kb  = Qb + NX;
    unsigned short* VTb = Kb + NX;   // V^T: [D_MODEL][MROWS]
    unsigned short* Ab  = VTb + NX;

    cvt_kernel<<<(unsigned)(NX / 1024), 256, 0, stream>>>(x,  xb,  (int)(NX / 4));
    cvt_kernel<<<(unsigned)(NW / 1024), 256, 0, stream>>>(wq, wqb, (int)(NW / 4));
    cvt_kernel<<<(unsigned)(NW / 1024), 256, 0, stream>>>(wk, wkb, (int)(NW / 4));
    cvt_kernel<<<(unsigned)(NW / 1024), 256, 0, stream>>>(wv, wvb, (int)(NW / 4));
    cvt_kernel<<<(unsigned)(NW / 1024), 256, 0, stream>>>(wo, wob, (int)(NW / 4));

    gemm_bt<1, unsigned short><<<512, 256, 0, stream>>>(xb, wqb, bq, Qb, MROWS, D_MODEL, D_MODEL);
    gemm_bt<1, unsigned short><<<512, 256, 0, stream>>>(xb, wkb, bk, Kb, MROWS, D_MODEL, D_MODEL);
    gemm_bt<2, unsigned short><<<512, 256, 0, stream>>>(xb, wvb, bv, VTb, MROWS, D_MODEL, D_MODEL);

    flash_attn2<<<512, 256, 0, stream>>>(Qb, Kb, VTb, Ab);

    gemm_bt<0, float><<<512, 256, 0, stream>>>(Ab, wob, bo, out, MROWS, D_MODEL, D_MODEL);
}

// Round 3
// 280.369 us; speedup vs baseline: 1.3048x; 1.0807x over previous
//
#include <hip/hip_runtime.h>
#include <cstdint>
#include <cstddef>

#define D_MODEL 2048
#define SEQ 2048
#define BATCH 2
#define HEADS 16
#define DH 128
#define MROWS (BATCH * SEQ) /* 4096 */

typedef __attribute__((ext_vector_type(8))) short short8;
typedef __attribute__((ext_vector_type(4))) float f32x4;
typedef __attribute__((ext_vector_type(16))) float f32x16;
typedef __attribute__((ext_vector_type(2))) unsigned int uint2e;

__device__ __forceinline__ unsigned short f2bf(float f) {
    unsigned int u = __builtin_bit_cast(unsigned int, f);
    u += 0x7fffu + ((u >> 16) & 1u);   // round-to-nearest-even
    return (unsigned short)(u >> 16);
}

__device__ __forceinline__ unsigned int cvt_pk_bf16(float lo, float hi) {
    unsigned int w;
    asm("v_cvt_pk_bf16_f32 %0, %1, %2" : "=v"(w) : "v"(lo), "v"(hi));
    return w;
}

// (r0,r1) semantics: r0 = {lanes<32: x, lanes>=32: y from lane-32}
//                    r1 = {lanes<32: x from lane+32, lanes>=32: y}
__device__ __forceinline__ void swap32(unsigned int& x, unsigned int& y) {
#if __has_builtin(__builtin_amdgcn_permlane32_swap)
    uint2e r = __builtin_amdgcn_permlane32_swap(x, y, false, false);
    x = r[0]; y = r[1];
#else
    const int hi = (threadIdx.x >> 5) & 1;
    const unsigned int gx = (unsigned int)__shfl_xor((int)x, 32);
    const unsigned int gy = (unsigned int)__shfl_xor((int)y, 32);
    const unsigned int nx = hi ? gy : x;
    const unsigned int ny = hi ? y : gx;
    x = nx; y = ny;
#endif
}

__device__ __forceinline__ void gload_lds16(const unsigned short* g, unsigned short* l) {
    __builtin_amdgcn_global_load_lds(
        (const __attribute__((address_space(1))) void*)g,
        (__attribute__((address_space(3))) void*)l, 16, 0, 0);
}

// ---------------- fp32 -> bf16 conversion ----------------
__global__ __launch_bounds__(256) void cvt_kernel(const float* __restrict__ in,
                                                  unsigned short* __restrict__ out, int n4) {
    int i = blockIdx.x * 256 + threadIdx.x;
    if (i < n4) {
        const float4 v = reinterpret_cast<const float4*>(in)[i];
        ushort4 o;
        o.x = f2bf(v.x); o.y = f2bf(v.y); o.z = f2bf(v.z); o.w = f2bf(v.w);
        reinterpret_cast<ushort4*>(out)[i] = o;
    }
}

// ---------------- GEMM: C[m][n] = sum_k A[m][k]*B[n][k] + bias[n] ----------------
// MODE 0: float out row-major. MODE 1: bf16 out row-major. MODE 2: bf16 out TRANSPOSED.
template <int MODE, typename OUT_T>
__global__ __launch_bounds__(256, 2)
void gemm_bt(const unsigned short* __restrict__ A, const unsigned short* __restrict__ B,
             const float* __restrict__ bias, OUT_T* __restrict__ C,
             int M, int N, int K) {
    constexpr int BM = 128, BN = 128, BK = 64;
    __shared__ unsigned short As[BM * BK];
    __shared__ unsigned short Bs[BN * BK];

    const int tid  = threadIdx.x;
    const int lane = tid & 63;
    const int wid  = tid >> 6;
    const int ntile = N / BN;
    const int mt = blockIdx.x / ntile;
    const int nt = blockIdx.x % ntile;
    const int m0 = mt * BM, n0 = nt * BN;

    f32x4 acc[4][4] = {};

    const int srow = wid * 32 + (lane >> 3);
    const int schk = lane & 7;
    const int wr = wid >> 1, wc = wid & 1;
    const int fr = lane & 15;
    const int fg = lane >> 4;

    for (int k0 = 0; k0 < K; k0 += BK) {
#pragma unroll
        for (int j = 0; j < 4; ++j) {
            const int row = srow + j * 8;
            const int gch = schk ^ (row & 7);
            gload_lds16(A + (size_t)(m0 + row) * K + k0 + gch * 8,
                        As + (wid * 32 + j * 8) * BK);
            gload_lds16(B + (size_t)(n0 + row) * K + k0 + gch * 8,
                        Bs + (wid * 32 + j * 8) * BK);
        }
        __syncthreads();
#pragma unroll
        for (int kk = 0; kk < 2; ++kk) {
            short8 af[4], bf[4];
#pragma unroll
            for (int i = 0; i < 4; ++i) {
                const int ra = wr * 64 + i * 16 + fr;
                af[i] = *(const short8*)&As[ra * BK + (((kk * 4) + fg) ^ (ra & 7)) * 8];
                const int rb = wc * 64 + i * 16 + fr;
                bf[i] = *(const short8*)&Bs[rb * BK + (((kk * 4) + fg) ^ (rb & 7)) * 8];
            }
#pragma unroll
            for (int mi = 0; mi < 4; ++mi)
#pragma unroll
                for (int ni = 0; ni < 4; ++ni)
                    acc[mi][ni] = __builtin_amdgcn_mfma_f32_16x16x32_bf16(
                        af[mi], bf[ni], acc[mi][ni], 0, 0, 0);
        }
        __syncthreads();
    }

#pragma unroll
    for (int mi = 0; mi < 4; ++mi) {
#pragma unroll
        for (int ni = 0; ni < 4; ++ni) {
            const int col = n0 + wc * 64 + ni * 16 + fr;
            const float bv = bias[col];
            if constexpr (MODE == 2) {
                const int row_b = m0 + wr * 64 + mi * 16 + fg * 4;
                ushort4 o4;
                o4.x = f2bf(acc[mi][ni][0] + bv);
                o4.y = f2bf(acc[mi][ni][1] + bv);
                o4.z = f2bf(acc[mi][ni][2] + bv);
                o4.w = f2bf(acc[mi][ni][3] + bv);
                *(ushort4*)&C[(size_t)col * M + row_b] = o4;
            } else {
#pragma unroll
                for (int r = 0; r < 4; ++r) {
                    const int row = m0 + wr * 64 + mi * 16 + fg * 4 + r;
                    const float v = acc[mi][ni][r] + bv;
                    if constexpr (MODE == 1) {
                        C[(size_t)row * N + col] = (OUT_T)f2bf(v);
                    } else {
                        C[(size_t)row * N + col] = v;
                    }
                }
            }
        }
    }
}

// ---------------- flash attention v3: dbuf + defer-max + cvt_pk/permlane ----------------
__global__ __launch_bounds__(256, 2)
void flash_attn3(const unsigned short* __restrict__ Q, const unsigned short* __restrict__ Kg,
                 const unsigned short* __restrict__ VT, unsigned short* __restrict__ O) {
    constexpr int KVB = 64;
    constexpr int NT = SEQ / KVB;
    __shared__ unsigned short Ks[2 * KVB * DH];   // dbuf, chunk^(row&7) swizzled
    __shared__ unsigned short Vs[2 * DH * KVB];   // dbuf, V^T, chunk^(d&7) swizzled

    const int tid  = threadIdx.x;
    const int lane = tid & 63;
    const int wid  = tid >> 6;
    const int l31  = lane & 31;
    const int hi   = lane >> 5;

    const int qt = blockIdx.x & 15;
    const int bh = blockIdx.x >> 4;
    const int b = bh >> 4, h = bh & 15;
    const int qrow = qt * 128 + wid * 32 + l31;

    const unsigned short* Qp = Q + ((size_t)b * SEQ + qrow) * D_MODEL + h * DH;
    const unsigned short* Kp = Kg + (size_t)b * SEQ * D_MODEL + h * DH;
    const unsigned short* Vp = VT + (size_t)(h * DH) * MROWS + (size_t)b * SEQ;

    // Q B-frags: lane holds Q[q=own][d = kk*16 + hi*8 .. +7]
    short8 qf[8];
#pragma unroll
    for (int kk = 0; kk < 8; ++kk)
        qf[kk] = *(const short8*)(Qp + kk * 16 + hi * 8);

    f32x16 acc[4] = {};
    float m_run = -1e30f, l_run = 0.f;
    const float Cc = 0.088388347648318447f * 1.4426950408889634f;  // scale * log2(e)
    const float THR = 8.0f / Cc;

    // swizzled chunk offsets (elements) shared by K and V fragment reads
    int co[8];
#pragma unroll
    for (int kk = 0; kk < 8; ++kk) co[kk] = ((kk * 2 + hi) ^ (l31 & 7)) * 8;

    // staging source offsets (inverse-swizzled; LDS dest linear)
    int kroff[4], vroff[4];
#pragma unroll
    for (int q = 0; q < 4; ++q) {
        const int row_l = wid * 16 + q * 4 + (lane >> 4);
        kroff[q] = row_l * D_MODEL + ((lane & 15) ^ (row_l & 7)) * 8;
        const int d_l = wid * 32 + q * 8 + (lane >> 3);
        vroff[q] = d_l * MROWS + ((lane & 7) ^ (d_l & 7)) * 8;
    }
    unsigned short* KsW = Ks + (wid * 16) * DH;
    unsigned short* VsW = Vs + (wid * 32) * KVB;

    // prologue: stage tile 0 into buffer 0
#pragma unroll
    for (int q = 0; q < 4; ++q) {
        gload_lds16(Kp + kroff[q], KsW + q * 4 * DH);
        gload_lds16(Vp + vroff[q], VsW + q * 8 * KVB);
    }
    __syncthreads();

    for (int t = 0; t < NT; ++t) {
        const int cur = t & 1;
        // ---- issue next-tile stage early (hides under compute; drained at barrier) ----
        if (t + 1 < NT) {
            const unsigned short* Kt = Kp + (size_t)((t + 1) * KVB) * D_MODEL;
            const unsigned short* Vt = Vp + (t + 1) * KVB;
            unsigned short* kd = KsW + (cur ^ 1) * (KVB * DH);
            unsigned short* vd = VsW + (cur ^ 1) * (DH * KVB);
#pragma unroll
            for (int q = 0; q < 4; ++q) {
                gload_lds16(Kt + kroff[q], kd + q * 4 * DH);
                gload_lds16(Vt + vroff[q], vd + q * 8 * KVB);
            }
        }
        const unsigned short* Kc = Ks + cur * (KVB * DH);
        const unsigned short* Vc = Vs + cur * (DH * KVB);

        // ---- swapped QK^T: St[kv][q], col=lane&31=q ----
        f32x16 st0 = {}, st1 = {};
        __builtin_amdgcn_s_setprio(1);
#pragma unroll
        for (int kk = 0; kk < 8; ++kk) {
            const short8 kf0 = *(const short8*)&Kc[l31 * DH + co[kk]];
            const short8 kf1 = *(const short8*)&Kc[(32 + l31) * DH + co[kk]];
            st0 = __builtin_amdgcn_mfma_f32_32x32x16_bf16(kf0, qf[kk], st0, 0, 0, 0);
            st1 = __builtin_amdgcn_mfma_f32_32x32x16_bf16(kf1, qf[kk], st1, 0, 0, 0);
        }
        __builtin_amdgcn_s_setprio(0);

        // ---- online softmax with defer-max (T13) ----
        float lm = -1e30f;
#pragma unroll
        for (int r = 0; r < 16; ++r) lm = fmaxf(lm, fmaxf(st0[r], st1[r]));
        {
            unsigned int a = __builtin_bit_cast(unsigned int, lm), bb = a;
            swap32(a, bb);
            lm = fmaxf(lm, __builtin_bit_cast(float, hi ? a : bb));
        }
        if (__any(lm > m_run + THR)) {
            const float mn = fmaxf(m_run, lm);
            const float sf = __builtin_amdgcn_exp2f((m_run - mn) * Cc);
            m_run = mn;
            l_run *= sf;
#pragma unroll
            for (int db = 0; db < 4; ++db)
#pragma unroll
                for (int r = 0; r < 16; ++r) acc[db][r] *= sf;
        }
        const float mc = m_run * Cc;
        float p0[16], p1[16];
        float ps = 0.f;
#pragma unroll
        for (int r = 0; r < 16; ++r) {
            p0[r] = __builtin_amdgcn_exp2f(__builtin_fmaf(st0[r], Cc, -mc));
            p1[r] = __builtin_amdgcn_exp2f(__builtin_fmaf(st1[r], Cc, -mc));
            ps += p0[r] + p1[r];
        }
        {
            unsigned int a = __builtin_bit_cast(unsigned int, ps), bb = a;
            swap32(a, bb);
            ps += __builtin_bit_cast(float, hi ? a : bb);
        }
        l_run += ps;

        // ---- P -> bf16 (v_cvt_pk) + half-exchange (permlane32_swap) -> B-frags ----
        unsigned int W0[8], W1[8];
#pragma unroll
        for (int tt = 0; tt < 8; ++tt) {
            W0[tt] = cvt_pk_bf16(p0[2 * tt], p0[2 * tt + 1]);
            W1[tt] = cvt_pk_bf16(p1[2 * tt], p1[2 * tt + 1]);
        }
        swap32(W0[0], W0[2]); swap32(W0[1], W0[3]);
        swap32(W0[4], W0[6]); swap32(W0[5], W0[7]);
        swap32(W1[0], W1[2]); swap32(W1[1], W1[3]);
        swap32(W1[4], W1[6]); swap32(W1[5], W1[7]);
        short8 pf[4];
        {
            uint4 f;
            f.x = W0[0]; f.y = W0[1]; f.z = W0[2]; f.w = W0[3];
            pf[0] = __builtin_bit_cast(short8, f);
            f.x = W0[4]; f.y = W0[5]; f.z = W0[6]; f.w = W0[7];
            pf[1] = __builtin_bit_cast(short8, f);
            f.x = W1[0]; f.y = W1[1]; f.z = W1[2]; f.w = W1[3];
            pf[2] = __builtin_bit_cast(short8, f);
            f.x = W1[4]; f.y = W1[5]; f.z = W1[6]; f.w = W1[7];
            pf[3] = __builtin_bit_cast(short8, f);
        }

        // ---- swapped PV: O^T[d][q] += V^T-frag x P-frag ----
        __builtin_amdgcn_s_setprio(1);
#pragma unroll
        for (int db = 0; db < 4; ++db) {
#pragma unroll
            for (int kk16 = 0; kk16 < 4; ++kk16) {
                const short8 vf = *(const short8*)&Vc[(db * 32 + l31) * KVB + co[kk16]];
                acc[db] = __builtin_amdgcn_mfma_f32_32x32x16_bf16(vf, pf[kk16], acc[db], 0, 0, 0);
            }
        }
        __builtin_amdgcn_s_setprio(0);
        __syncthreads();
    }

    // ---- epilogue ----
    const float inv_l = 1.0f / l_run;
    unsigned short* Op = O + ((size_t)b * SEQ + qrow) * D_MODEL + h * DH;
#pragma unroll
    for (int db = 0; db < 4; ++db)
#pragma unroll
        for (int g = 0; g < 4; ++g) {
            ushort4 o4;
            o4.x = f2bf(acc[db][4 * g + 0] * inv_l);
            o4.y = f2bf(acc[db][4 * g + 1] * inv_l);
            o4.z = f2bf(acc[db][4 * g + 2] * inv_l);
            o4.w = f2bf(acc[db][4 * g + 3] * inv_l);
            *(ushort4*)(Op + db * 32 + g * 8 + hi * 4) = o4;
        }
}

// ---------------- host launch ----------------
extern "C" void kernel_launch(void* const* d_in, const int* in_sizes, int n_in,
                              void* d_out, int out_size, void* d_ws, size_t ws_size,
                              hipStream_t stream) {
    (void)in_sizes; (void)n_in; (void)out_size; (void)ws_size;
    const float* x  = (const float*)d_in[0];
    const float* wq = (const float*)d_in[1];
    const float* bq = (const float*)d_in[2];
    const float* wk = (const float*)d_in[3];
    const float* bk = (const float*)d_in[4];
    const float* wv = (const float*)d_in[5];
    const float* bv = (const float*)d_in[6];
    const float* wo = (const float*)d_in[7];
    const float* bo = (const float*)d_in[8];
    float* out = (float*)d_out;

    unsigned short* ws = (unsigned short*)d_ws;
    const size_t NX = (size_t)MROWS * D_MODEL;
    const size_t NW = (size_t)D_MODEL * D_MODEL;
    unsigned short* xb  = ws;
    unsigned short* wqb = xb + NX;
    unsigned short* wkb = wqb + NW;
    unsigned short* wvb = wkb + NW;
    unsigned short* wob = wvb + NW;
    unsigned short* Qb  = wob + NW;
    unsigned short* Kb  = Qb + NX;
    unsigned short* VTb = Kb + NX;   // V^T: [D_MODEL][MROWS]
    unsigned short* Ab  = VTb + NX;

    cvt_kernel<<<(unsigned)(NX / 1024), 256, 0, stream>>>(x,  xb,  (int)(NX / 4));
    cvt_kernel<<<(unsigned)(NW / 1024), 256, 0, stream>>>(wq, wqb, (int)(NW / 4));
    cvt_kernel<<<(unsigned)(NW / 1024), 256, 0, stream>>>(wk, wkb, (int)(NW / 4));
    cvt_kernel<<<(unsigned)(NW / 1024), 256, 0, stream>>>(wv, wvb, (int)(NW / 4));
    cvt_kernel<<<(unsigned)(NW / 1024), 256, 0, stream>>>(wo, wob, (int)(NW / 4));

    gemm_bt<1, unsigned short><<<512, 256, 0, stream>>>(xb, wqb, bq, Qb, MROWS, D_MODEL, D_MODEL);
    gemm_bt<1, unsigned short><<<512, 256, 0, stream>>>(xb, wkb, bk, Kb, MROWS, D_MODEL, D_MODEL);
    gemm_bt<2, unsigned short><<<512, 256, 0, stream>>>(xb, wvb, bv, VTb, MROWS, D_MODEL, D_MODEL);

    flash_attn3<<<512, 256, 0, stream>>>(Qb, Kb, VTb, Ab);

    gemm_bt<0, float><<<512, 256, 0, stream>>>(Ab, wob, bo, out, MROWS, D_MODEL, D_MODEL);
}